// Round 7
// baseline (191.907 us; speedup 1.0000x reference)
//
#include <hip/hip_runtime.h>
#include <hip/hip_bf16.h>

typedef __bf16 bf16;
typedef __bf16 bf16x8 __attribute__((ext_vector_type(8)));
typedef float f32x4 __attribute__((ext_vector_type(4)));

__device__ __forceinline__ void gload_lds16(const void* g, void* l) {
  __builtin_amdgcn_global_load_lds(
      (const __attribute__((address_space(1))) void*)g,
      (__attribute__((address_space(3))) void*)l, 16, 0, 0);
}

// ---------------------------------------------------------------------------
// C = A[M,K] @ B[N,K]^T (row-major, K inner). bf16 in, f32 accum.
// EPI=0: f32 store. EPI=1: sigmoid -> bf16 store.
// 128x128 tile, BK=32, 256 thr = 4 waves (2x2), 4x4 16x16x32 MFMA per wave.
// A-OPERAND DIRECT FROM GLOBAL: a lane's A-fragment (row wm+i*16+lrow, 16B at
// kslot) is 16 full 64B lines per instr across the wave -> perfectly
// coalesced; loaded into VGPRs depth-2 (ping-pong sets, refilled AFTER the
// consuming MFMA -> WAR-safe).  Only B staged to LDS (8KB/iter) via
// gload_lds, 4-buffer ring (32KB), r5-proven 0-conflict swizzle.
// Constant counted wait: per iter issue order [stageB(t+2) 2, loadA(t+2) 4];
// top-of-iter vmcnt(6) retires exactly {B(t),A(t)} (in-order retirement),
// leaving {B(t+1),A(t+1)} in flight.  One s_barrier per iter.
// Ring safety: write target (t+2)&3 never equals any buf read by waves
// within barrier skew 1 (t-1,t,t+1 mod 4 all differ).
// ---------------------------------------------------------------------------
template <int EPI>
__global__ __launch_bounds__(256, 3) void gemm_areg(
    const bf16* __restrict__ A, const bf16* __restrict__ Bw,
    void* __restrict__ C, int M, int N, int K) {
  __shared__ __align__(16) char smem[32768];  // 4 x 8KB B buffers
  const int tid = threadIdx.x;
  const int lane = tid & 63;
  const int wave = tid >> 6;

  const int nb = N >> 7;
  const int nwg = gridDim.x;
  const int q8 = nwg >> 3;  // grids divisible by 8
  const int tile = ((int)blockIdx.x & 7) * q8 + ((int)blockIdx.x >> 3);
  const int m0 = (tile / nb) << 7;
  const int n0 = (tile % nb) << 7;

  const int wm = (wave >> 1) << 6;
  const int wn = (wave & 1) << 6;

  f32x4 acc[4][4] = {};

  // ---- B staging constants (r5-proven pattern, 8 chunks = 128 rows) ----
  const int r_in = lane >> 2;                        // row within 16-row chunk
  const int swz = ((lane >> 3) & 3) << 4;            // ((r_in>>1)&3)<<4
  const int scol = (((lane & 3) << 4) ^ swz) >> 1;   // source col (elements)

  auto stageB = [&](int t, int buf) {
    const int k0 = t << 5;
#pragma unroll
    for (int c = 0; c < 2; ++c) {
      const int chunk = wave + (c << 2);  // wave-uniform 0..7
      char* ldst = smem + buf * 8192 + chunk * 1024 + (lane << 4);
      const int row = n0 + (chunk << 4) + r_in;
      gload_lds16(Bw + (size_t)row * K + k0 + scol, ldst);
    }
  };

  // ---- B ds_read constants (0-conflict proven) ----
  const int lrow = lane & 15;
  const int koff = ((lane >> 4) << 4) ^ (((lrow >> 1) & 3) << 4);

  // ---- A direct-load bases: lane's frag i = row m0+wm+i*16+lrow, 8 elems at
  //      (lane>>4)*8 + t*32 ----
  const bf16* a0 = A + (size_t)(m0 + wm + 0  + lrow) * K + ((lane >> 4) << 3);
  const bf16* a1 = A + (size_t)(m0 + wm + 16 + lrow) * K + ((lane >> 4) << 3);
  const bf16* a2 = A + (size_t)(m0 + wm + 32 + lrow) * K + ((lane >> 4) << 3);
  const bf16* a3 = A + (size_t)(m0 + wm + 48 + lrow) * K + ((lane >> 4) << 3);

  const int nt = K >> 5;  // 32 for K=1024
  bf16x8 afA[4], afB[4];

  // ---- prologue: B(0),A(0),B(1),A(1) issued (12 outstanding) ----
  stageB(0, 0);
  afA[0] = *(const bf16x8*)(a0); afA[1] = *(const bf16x8*)(a1);
  afA[2] = *(const bf16x8*)(a2); afA[3] = *(const bf16x8*)(a3);
  stageB(1, 1);
  afB[0] = *(const bf16x8*)(a0 + 32); afB[1] = *(const bf16x8*)(a1 + 32);
  afB[2] = *(const bf16x8*)(a2 + 32); afB[3] = *(const bf16x8*)(a3 + 32);

  auto body = [&](int t, bf16x8(&af)[4]) {
    if (t == nt - 1) {
      asm volatile("s_waitcnt vmcnt(0)" ::: "memory");
    } else {
      asm volatile("s_waitcnt vmcnt(6)" ::: "memory");  // {B(t),A(t)} retired
    }
    __builtin_amdgcn_s_barrier();
    __builtin_amdgcn_sched_barrier(0);

    bf16x8 bg[4];
    const char* base = smem + (t & 3) * 8192;
#pragma unroll
    for (int j = 0; j < 4; ++j)
      bg[j] = *(const bf16x8*)(base + (wn + (j << 4) + lrow) * 64 + koff);

    if (t + 2 < nt) stageB(t + 2, (t + 2) & 3);

    asm volatile("s_waitcnt lgkmcnt(0)" ::: "memory");
    __builtin_amdgcn_sched_barrier(0);  // rule #18

#pragma unroll
    for (int i = 0; i < 4; ++i)
#pragma unroll
      for (int j = 0; j < 4; ++j)
        acc[i][j] =
            __builtin_amdgcn_mfma_f32_16x16x32_bf16(af[i], bg[j], acc[i][j], 0, 0, 0);
    __builtin_amdgcn_sched_barrier(0);

    if (t + 2 < nt) {  // refill this set AFTER its last use (WAR via reg dep)
      const int ko = (t + 2) << 5;
      af[0] = *(const bf16x8*)(a0 + ko);
      af[1] = *(const bf16x8*)(a1 + ko);
      af[2] = *(const bf16x8*)(a2 + ko);
      af[3] = *(const bf16x8*)(a3 + ko);
    }
  };

  for (int t = 0; t < nt; t += 2) {
    body(t, afA);
    body(t + 1, afB);
  }

  // ---- epilogue: C/D layout col=lane&15, row=(lane>>4)*4+reg ----
  const int col0 = n0 + wn + lrow;
  const int rowb = m0 + wm + ((lane >> 4) << 2);
#pragma unroll
  for (int i = 0; i < 4; ++i)
#pragma unroll
    for (int j = 0; j < 4; ++j)
#pragma unroll
      for (int r = 0; r < 4; ++r) {
        const size_t idx = (size_t)(rowb + (i << 4) + r) * N + (col0 + (j << 4));
        const float v = acc[i][j][r];
        if (EPI == 1) {
          ((bf16*)C)[idx] = (bf16)(1.0f / (1.0f + __expf(-v)));
        } else {
          ((float*)C)[idx] = v;
        }
      }
}

// ---------------------------------------------------------------------------
// Windowed Hamming attention + gate.  One thread per (b,s,h).
// ---------------------------------------------------------------------------
__global__ __launch_bounds__(256) void rosa_attn(
    const bf16* __restrict__ qkv, const float* __restrict__ emb0,
    const float* __restrict__ emb1, bf16* __restrict__ G) {
  const int t = blockIdx.x * 256 + threadIdx.x;
  const int row = t >> 7;
  const int h = t & 127;
  const int sp = row & 4095;

  const bf16* qptr = qkv + (size_t)row * 3072 + h * 8;
  bf16x8 qv = *(const bf16x8*)qptr;
  float qb[8], qsum = 0.f;
#pragma unroll
  for (int c = 0; c < 8; ++c) {
    qb[c] = (float)qv[c];
    qsum += qb[c];
  }

  float oacc[8] = {};
  float wsum = 0.f;
  const int wmax = (sp + 1 < 8) ? (sp + 1) : 8;
  const float scale = 0.35355339059327373f;

  for (int d = 0; d < wmax; ++d) {
    const bf16* base = qkv + (size_t)(row - d) * 3072 + h * 8;
    bf16x8 kv = *(const bf16x8*)(base + 1024);
    bf16x8 vv = *(const bf16x8*)(base + 2048);
    float dot = 0.f, ksum = 0.f;
#pragma unroll
    for (int c = 0; c < 8; ++c) {
      const float kb = (float)kv[c];
      dot += qb[c] * kb;
      ksum += kb;
    }
    const float score = (8.0f + 2.0f * dot - qsum - ksum) * scale;
    const float w = __expf(score);
    wsum += w;
#pragma unroll
    for (int c = 0; c < 8; ++c) oacc[c] += w * (float)vv[c];
  }

  const float inv = 1.0f / wsum;
  const int e0i = h * 8;
  bf16x8 outv;
#pragma unroll
  for (int c = 0; c < 8; ++c) {
    const float o = oacc[c] * inv;
    const float e0 = emb0[e0i + c], e1 = emb1[e0i + c];
    outv[c] = (bf16)(e0 + (e1 - e0) * o);
  }
  *(bf16x8*)(G + (size_t)row * 1024 + h * 8) = outv;
}

// ---------------------------------------------------------------------------
// One launch converts X, Wq, Wk, Wv, Wo -> bf16.  8 f32 per thread.
// ---------------------------------------------------------------------------
__global__ __launch_bounds__(256) void cvt_all(
    const float* __restrict__ X, const float* __restrict__ Wq,
    const float* __restrict__ Wk, const float* __restrict__ Wv,
    const float* __restrict__ Wo, bf16* __restrict__ Xb,
    bf16* __restrict__ Wqkvb, bf16* __restrict__ Wob) {
  const int b = blockIdx.x;
  const float* src;
  bf16* dst;
  int off;
  if (b < 4096)      { src = X;  dst = Xb;             off = b; }
  else if (b < 4608) { src = Wq; dst = Wqkvb;          off = b - 4096; }
  else if (b < 5120) { src = Wk; dst = Wqkvb + 1048576; off = b - 4608; }
  else if (b < 5632) { src = Wv; dst = Wqkvb + 2097152; off = b - 5120; }
  else               { src = Wo; dst = Wob;            off = b - 5632; }
  const int i = (off * 256 + threadIdx.x) * 8;
  const float4 a = *(const float4*)(src + i);
  const float4 c = *(const float4*)(src + i + 4);
  bf16x8 o;
  o[0] = (bf16)a.x; o[1] = (bf16)a.y; o[2] = (bf16)a.z; o[3] = (bf16)a.w;
  o[4] = (bf16)c.x; o[5] = (bf16)c.y; o[6] = (bf16)c.z; o[7] = (bf16)c.w;
  *(bf16x8*)(dst + i) = o;
}

// ---------------------------------------------------------------------------
extern "C" void kernel_launch(void* const* d_in, const int* in_sizes, int n_in,
                              void* d_out, int out_size, void* d_ws,
                              size_t ws_size, hipStream_t stream) {
  const float* X = (const float*)d_in[0];
  const float* Wq = (const float*)d_in[1];
  const float* Wk = (const float*)d_in[2];
  const float* Wv = (const float*)d_in[3];
  const float* Wo = (const float*)d_in[4];
  const float* emb0 = (const float*)d_in[5];
  const float* emb1 = (const float*)d_in[6];

  char* ws = (char*)d_ws;
  bf16* Xb    = (bf16*)(ws + 0);          // 8192*1024   (16 MB)
  bf16* Wqkvb = (bf16*)(ws + 16777216);   // 3072*1024   (6 MB)
  bf16* Wob   = (bf16*)(ws + 23068672);   // 1024*1024   (2 MB)
  bf16* QKVb  = (bf16*)(ws + 25165824);   // 8192*3072   (48 MB)
  bf16* G     = (bf16*)(ws + 75497472);   // 8192*1024   (16 MB)
  float* out  = (float*)d_out;

  // all f32 -> bf16 conversions in one launch
  cvt_all<<<6144, 256, 0, stream>>>(X, Wq, Wk, Wv, Wo, Xb, Wqkvb, Wob);

  // fused QKV projection + sigmoid -> bf16 (M=8192, N=3072, K=1024)
  gemm_areg<1><<<64 * 24, 256, 0, stream>>>(Xb, Wqkvb, QKVb, 8192, 3072, 1024);

  // windowed attention + gate -> bf16
  rosa_attn<<<4096, 256, 0, stream>>>(QKVb, emb0, emb1, G);

  // output projection -> f32 (M=8192, N=1024, K=1024)
  gemm_areg<0><<<64 * 8, 256, 0, stream>>>(G, Wob, out, 8192, 1024, 1024);
}

// Round 8
// 124.542 us; speedup vs baseline: 1.5409x; 1.5409x over previous
//
#include <hip/hip_runtime.h>
#include <hip/hip_bf16.h>

typedef __bf16 bf16;
typedef __bf16 bf16x8 __attribute__((ext_vector_type(8)));
typedef float f32x4 __attribute__((ext_vector_type(4)));

__device__ __forceinline__ void gload_lds16(const void* g, void* l) {
  __builtin_amdgcn_global_load_lds(
      (const __attribute__((address_space(1))) void*)g,
      (__attribute__((address_space(3))) void*)l, 16, 0, 0);
}

// ---------------------------------------------------------------------------
// QKV GEMM: C = A[M,K] @ B[N,K]^T, 256x128 tile, BK=32, 512 thr = 8 waves
// (4M x 2N), 4x4 16x16x32 MFMA per wave (wave tile 64x64).
// r5-proven pieces: triple-buffered LDS (3 x 24KB), one s_barrier/iter,
// counted vmcnt(3) (stage(t) landed, stage(t+1) in flight, stage(t+2)
// issued after barrier), 0-conflict chunk swizzle (16-row x 64B chunks,
// source col16 ^= ((row>>1)&3)<<4, same XOR on ds_read).
// Sigmoid -> bf16 epilogue.
// ---------------------------------------------------------------------------
__global__ __launch_bounds__(512, 4) void gemm_qkv(
    const bf16* __restrict__ A, const bf16* __restrict__ Bw,
    bf16* __restrict__ C, int M, int N, int K) {
  __shared__ __align__(16) char smem[73728];  // 3 bufs: A 16KB + B 8KB each
  const int tid = threadIdx.x;
  const int lane = tid & 63;
  const int wave = tid >> 6;

  const int nb = N >> 7;  // 128-col tiles
  const int nwg = gridDim.x;
  const int q8 = nwg >> 3;  // grid divisible by 8
  const int tile = ((int)blockIdx.x & 7) * q8 + ((int)blockIdx.x >> 3);
  const int m0 = (tile / nb) << 8;
  const int n0 = (tile % nb) << 7;

  const int wm = (wave >> 1) << 6;  // 0..192
  const int wn = (wave & 1) << 6;   // 0/64

  f32x4 acc[4][4] = {};

  // staging: 24 chunks (16 rows x 64B each); chunk = wave + 8c, c=0..2
  const int r_in = lane >> 2;
  const int swz = ((lane >> 3) & 3) << 4;
  const int scol = (((lane & 3) << 4) ^ swz) >> 1;

  auto stage = [&](int t, int buf) {
    const int k0 = t << 5;
#pragma unroll
    for (int c = 0; c < 3; ++c) {
      const int chunk = wave + (c << 3);  // wave-uniform 0..23
      char* ldst = smem + buf * 24576 + chunk * 1024 + (lane << 4);
      const bf16* gsrc;
      if (chunk < 16) {
        const int row = m0 + (chunk << 4) + r_in;
        gsrc = A + (size_t)row * K + k0 + scol;
      } else {
        const int row = n0 + ((chunk - 16) << 4) + r_in;
        gsrc = Bw + (size_t)row * K + k0 + scol;
      }
      gload_lds16(gsrc, ldst);
    }
  };

  const int lrow = lane & 15;
  const int koff = ((lane >> 4) << 4) ^ (((lrow >> 1) & 3) << 4);

  const int nt = K >> 5;  // 32

  stage(0, 0);
  stage(1, 1);

  int buf = 0;
  for (int t = 0; t < nt; ++t) {
    if (t == nt - 1) {
      asm volatile("s_waitcnt vmcnt(0)" ::: "memory");
    } else {
      asm volatile("s_waitcnt vmcnt(3)" ::: "memory");  // stage(t) landed
    }
    __builtin_amdgcn_s_barrier();
    __builtin_amdgcn_sched_barrier(0);

    bf16x8 af[4], bg[4];
    const char* base = smem + buf * 24576;
#pragma unroll
    for (int i = 0; i < 4; ++i) {
      af[i] = *(const bf16x8*)(base + (wm + (i << 4) + lrow) * 64 + koff);
      bg[i] = *(const bf16x8*)(base + 16384 + (wn + (i << 4) + lrow) * 64 + koff);
    }

    if (t + 2 < nt) {
      int pb = buf + 2;
      if (pb >= 3) pb -= 3;
      stage(t + 2, pb);
    }

    asm volatile("s_waitcnt lgkmcnt(0)" ::: "memory");
    __builtin_amdgcn_sched_barrier(0);  // rule #18

#pragma unroll
    for (int i = 0; i < 4; ++i)
#pragma unroll
      for (int j = 0; j < 4; ++j)
        acc[i][j] =
            __builtin_amdgcn_mfma_f32_16x16x32_bf16(af[i], bg[j], acc[i][j], 0, 0, 0);

    if (++buf == 3) buf = 0;
  }

  // epilogue: sigmoid -> bf16; C/D layout col=lane&15, row=(lane>>4)*4+reg
  const int col0 = n0 + wn + lrow;
  const int rowb = m0 + wm + ((lane >> 4) << 2);
#pragma unroll
  for (int i = 0; i < 4; ++i)
#pragma unroll
    for (int j = 0; j < 4; ++j)
#pragma unroll
      for (int r = 0; r < 4; ++r) {
        const size_t idx = (size_t)(rowb + (i << 4) + r) * N + (col0 + (j << 4));
        C[idx] = (bf16)(1.0f / (1.0f + __expf(-acc[i][j][r])));
      }
}

// ---------------------------------------------------------------------------
// Output GEMM: r5 structure exactly (128x128, BK=32, 4 waves, triple buffer,
// counted vmcnt(4)).  f32 store.
// ---------------------------------------------------------------------------
__global__ __launch_bounds__(256, 3) void gemm_out(
    const bf16* __restrict__ A, const bf16* __restrict__ Bw,
    float* __restrict__ C, int M, int N, int K) {
  __shared__ __align__(16) char smem[49152];
  const int tid = threadIdx.x;
  const int lane = tid & 63;
  const int wave = tid >> 6;

  const int nb = N >> 7;
  const int nwg = gridDim.x;
  const int q8 = nwg >> 3;
  const int tile = ((int)blockIdx.x & 7) * q8 + ((int)blockIdx.x >> 3);
  const int m0 = (tile / nb) << 7;
  const int n0 = (tile % nb) << 7;

  const int wm = (wave >> 1) << 6;
  const int wn = (wave & 1) << 6;

  f32x4 acc[4][4] = {};

  const int r_in = lane >> 2;
  const int swz = ((lane >> 3) & 3) << 4;
  const int scol = (((lane & 3) << 4) ^ swz) >> 1;

  auto stage = [&](int t, int buf) {
    const int k0 = t << 5;
#pragma unroll
    for (int c = 0; c < 4; ++c) {
      const int chunk = wave + (c << 2);
      char* ldst = smem + buf * 16384 + chunk * 1024 + (lane << 4);
      const bf16* gsrc;
      if (chunk < 8) {
        const int row = m0 + (chunk << 4) + r_in;
        gsrc = A + (size_t)row * K + k0 + scol;
      } else {
        const int row = n0 + ((chunk - 8) << 4) + r_in;
        gsrc = Bw + (size_t)row * K + k0 + scol;
      }
      gload_lds16(gsrc, ldst);
    }
  };

  const int lrow = lane & 15;
  const int koff = ((lane >> 4) << 4) ^ (((lrow >> 1) & 3) << 4);

  const int nt = K >> 5;

  stage(0, 0);
  stage(1, 1);

  int buf = 0;
  for (int t = 0; t < nt; ++t) {
    if (t == nt - 1) {
      asm volatile("s_waitcnt vmcnt(0)" ::: "memory");
    } else {
      asm volatile("s_waitcnt vmcnt(4)" ::: "memory");
    }
    __builtin_amdgcn_s_barrier();
    __builtin_amdgcn_sched_barrier(0);

    bf16x8 af[4], bg[4];
    const char* base = smem + buf * 16384;
#pragma unroll
    for (int i = 0; i < 4; ++i) {
      af[i] = *(const bf16x8*)(base + (wm + (i << 4) + lrow) * 64 + koff);
      bg[i] = *(const bf16x8*)(base + 8192 + (wn + (i << 4) + lrow) * 64 + koff);
    }

    if (t + 2 < nt) {
      int pb = buf + 2;
      if (pb >= 3) pb -= 3;
      stage(t + 2, pb);
    }

    asm volatile("s_waitcnt lgkmcnt(0)" ::: "memory");
    __builtin_amdgcn_sched_barrier(0);

#pragma unroll
    for (int i = 0; i < 4; ++i)
#pragma unroll
      for (int j = 0; j < 4; ++j)
        acc[i][j] =
            __builtin_amdgcn_mfma_f32_16x16x32_bf16(af[i], bg[j], acc[i][j], 0, 0, 0);

    if (++buf == 3) buf = 0;
  }

  const int col0 = n0 + wn + lrow;
  const int rowb = m0 + wm + ((lane >> 4) << 2);
#pragma unroll
  for (int i = 0; i < 4; ++i)
#pragma unroll
    for (int j = 0; j < 4; ++j)
#pragma unroll
      for (int r = 0; r < 4; ++r) {
        const size_t idx = (size_t)(rowb + (i << 4) + r) * N + (col0 + (j << 4));
        C[idx] = acc[i][j][r];
      }
}

// ---------------------------------------------------------------------------
// Windowed Hamming attention + gate.  One thread per (b,s,h).
// ---------------------------------------------------------------------------
__global__ __launch_bounds__(256) void rosa_attn(
    const bf16* __restrict__ qkv, const float* __restrict__ emb0,
    const float* __restrict__ emb1, bf16* __restrict__ G) {
  const int t = blockIdx.x * 256 + threadIdx.x;
  const int row = t >> 7;
  const int h = t & 127;
  const int sp = row & 4095;

  const bf16* qptr = qkv + (size_t)row * 3072 + h * 8;
  bf16x8 qv = *(const bf16x8*)qptr;
  float qb[8], qsum = 0.f;
#pragma unroll
  for (int c = 0; c < 8; ++c) {
    qb[c] = (float)qv[c];
    qsum += qb[c];
  }

  float oacc[8] = {};
  float wsum = 0.f;
  const int wmax = (sp + 1 < 8) ? (sp + 1) : 8;
  const float scale = 0.35355339059327373f;

  for (int d = 0; d < wmax; ++d) {
    const bf16* base = qkv + (size_t)(row - d) * 3072 + h * 8;
    bf16x8 kv = *(const bf16x8*)(base + 1024);
    bf16x8 vv = *(const bf16x8*)(base + 2048);
    float dot = 0.f, ksum = 0.f;
#pragma unroll
    for (int c = 0; c < 8; ++c) {
      const float kb = (float)kv[c];
      dot += qb[c] * kb;
      ksum += kb;
    }
    const float score = (8.0f + 2.0f * dot - qsum - ksum) * scale;
    const float w = __expf(score);
    wsum += w;
#pragma unroll
    for (int c = 0; c < 8; ++c) oacc[c] += w * (float)vv[c];
  }

  const float inv = 1.0f / wsum;
  const int e0i = h * 8;
  bf16x8 outv;
#pragma unroll
  for (int c = 0; c < 8; ++c) {
    const float o = oacc[c] * inv;
    const float e0 = emb0[e0i + c], e1 = emb1[e0i + c];
    outv[c] = (bf16)(e0 + (e1 - e0) * o);
  }
  *(bf16x8*)(G + (size_t)row * 1024 + h * 8) = outv;
}

// ---------------------------------------------------------------------------
// One launch converts X, Wq, Wk, Wv, Wo -> bf16.  8 f32 per thread.
// ---------------------------------------------------------------------------
__global__ __launch_bounds__(256) void cvt_all(
    const float* __restrict__ X, const float* __restrict__ Wq,
    const float* __restrict__ Wk, const float* __restrict__ Wv,
    const float* __restrict__ Wo, bf16* __restrict__ Xb,
    bf16* __restrict__ Wqkvb, bf16* __restrict__ Wob) {
  const int b = blockIdx.x;
  const float* src;
  bf16* dst;
  int off;
  if (b < 4096)      { src = X;  dst = Xb;             off = b; }
  else if (b < 4608) { src = Wq; dst = Wqkvb;          off = b - 4096; }
  else if (b < 5120) { src = Wk; dst = Wqkvb + 1048576; off = b - 4608; }
  else if (b < 5632) { src = Wv; dst = Wqkvb + 2097152; off = b - 5120; }
  else               { src = Wo; dst = Wob;            off = b - 5632; }
  const int i = (off * 256 + threadIdx.x) * 8;
  const float4 a = *(const float4*)(src + i);
  const float4 c = *(const float4*)(src + i + 4);
  bf16x8 o;
  o[0] = (bf16)a.x; o[1] = (bf16)a.y; o[2] = (bf16)a.z; o[3] = (bf16)a.w;
  o[4] = (bf16)c.x; o[5] = (bf16)c.y; o[6] = (bf16)c.z; o[7] = (bf16)c.w;
  *(bf16x8*)(dst + i) = o;
}

// ---------------------------------------------------------------------------
extern "C" void kernel_launch(void* const* d_in, const int* in_sizes, int n_in,
                              void* d_out, int out_size, void* d_ws,
                              size_t ws_size, hipStream_t stream) {
  const float* X = (const float*)d_in[0];
  const float* Wq = (const float*)d_in[1];
  const float* Wk = (const float*)d_in[2];
  const float* Wv = (const float*)d_in[3];
  const float* Wo = (const float*)d_in[4];
  const float* emb0 = (const float*)d_in[5];
  const float* emb1 = (const float*)d_in[6];

  char* ws = (char*)d_ws;
  bf16* Xb    = (bf16*)(ws + 0);          // 8192*1024   (16 MB)
  bf16* Wqkvb = (bf16*)(ws + 16777216);   // 3072*1024   (6 MB)
  bf16* Wob   = (bf16*)(ws + 23068672);   // 1024*1024   (2 MB)
  bf16* QKVb  = (bf16*)(ws + 25165824);   // 8192*3072   (48 MB)
  bf16* G     = (bf16*)(ws + 75497472);   // 8192*1024   (16 MB)
  float* out  = (float*)d_out;

  // all f32 -> bf16 conversions in one launch
  cvt_all<<<6144, 256, 0, stream>>>(X, Wq, Wk, Wv, Wo, Xb, Wqkvb, Wob);

  // fused QKV projection + sigmoid -> bf16 (M=8192, N=3072, K=1024)
  // 256x128 tiles: (8192/256) * (3072/128) = 32 * 24 = 768 blocks
  gemm_qkv<<<768, 512, 0, stream>>>(Xb, Wqkvb, QKVb, 8192, 3072, 1024);

  // windowed attention + gate -> bf16
  rosa_attn<<<4096, 256, 0, stream>>>(QKVb, emb0, emb1, G);

  // output projection -> f32 (M=8192, N=1024, K=1024): 512 blocks of 128x128
  gemm_out<<<512, 256, 0, stream>>>(G, Wob, out, 8192, 1024, 1024);
}

// Round 9
// 99.587 us; speedup vs baseline: 1.9270x; 1.2506x over previous
//
#include <hip/hip_runtime.h>
#include <hip/hip_bf16.h>

typedef __bf16 bf16;
typedef __bf16 bf16x8 __attribute__((ext_vector_type(8)));
typedef int i32x4 __attribute__((ext_vector_type(4)));
typedef signed char scx8 __attribute__((ext_vector_type(8)));

__device__ __forceinline__ void gload_lds16(const void* g, void* l) {
  __builtin_amdgcn_global_load_lds(
      (const __attribute__((address_space(1))) void*)g,
      (__attribute__((address_space(3))) void*)l, 16, 0, 0);
}

// ---------------------------------------------------------------------------
// i8 GEMM core (r5-proven structure, byte-identical LDS geometry):
// C_i32 = A[M,K]i8 @ B[N,K]i8^T.  128x128 tile, BK=64 (64B rows), 256 thr =
// 4 waves (2x2), 4x4 mfma_i32_16x16x64_i8 per wave.  Triple-buffered LDS
// (3 x 16KB), one s_barrier/iter, counted vmcnt(4), 0-conflict XOR swizzle
// (source byte-col ^= ((row>>1)&3)<<4, same XOR on ds_read).
// EPI=1: sigmoid((sA[m]*sB[n])*acc) -> bf16.   EPI=0: (sB[n]/127)*acc +
// bias[n] -> f32 (A-scale fixed 1/127).
// ---------------------------------------------------------------------------
template <int EPI>
__global__ __launch_bounds__(256, 3) void gemm_i8(
    const signed char* __restrict__ A, const signed char* __restrict__ Bw,
    const float* __restrict__ sA, const float* __restrict__ sB,
    const float* __restrict__ bias, void* __restrict__ C, int M, int N, int K) {
  __shared__ __align__(16) char smem[49152];  // buf b at b*16K: A 8K, B 8K
  const int tid = threadIdx.x;
  const int lane = tid & 63;
  const int wave = tid >> 6;

  const int nb = N >> 7;
  const int nwg = gridDim.x;
  const int q8 = nwg >> 3;  // grids divisible by 8
  const int tile = ((int)blockIdx.x & 7) * q8 + ((int)blockIdx.x >> 3);
  const int m0 = (tile / nb) << 7;
  const int n0 = (tile % nb) << 7;

  const int wm = (wave >> 1) << 6;
  const int wn = (wave & 1) << 6;

  i32x4 acc[4][4] = {};

  // staging: 16 chunks of (16 rows x 64B); chunk = wave + 4c
  const int r_in = lane >> 2;                      // row within chunk
  const int swz = ((lane >> 3) & 3) << 4;          // bits1-2 of r_in
  const int scolb = ((lane & 3) << 4) ^ swz;       // source byte col

  auto stage = [&](int t, int buf) {
    const int k0 = t << 6;  // 64 bytes per iter
#pragma unroll
    for (int c = 0; c < 4; ++c) {
      const int chunk = wave + (c << 2);  // wave-uniform 0..15
      char* ldst = smem + buf * 16384 + chunk * 1024 + (lane << 4);
      const signed char* gsrc;
      if (chunk < 8) {
        const int row = m0 + (chunk << 4) + r_in;
        gsrc = A + (size_t)row * K + k0 + scolb;
      } else {
        const int row = n0 + ((chunk - 8) << 4) + r_in;
        gsrc = Bw + (size_t)row * K + k0 + scolb;
      }
      gload_lds16(gsrc, ldst);
    }
  };

  const int lrow = lane & 15;
  const int koff = ((lane >> 4) << 4) ^ (((lrow >> 1) & 3) << 4);

  const int nt = K >> 6;  // 16 for K=1024

  stage(0, 0);
  stage(1, 1);

  int buf = 0;
  for (int t = 0; t < nt; ++t) {
    if (t == nt - 1) {
      asm volatile("s_waitcnt vmcnt(0)" ::: "memory");
    } else {
      asm volatile("s_waitcnt vmcnt(4)" ::: "memory");  // stage(t) landed
    }
    __builtin_amdgcn_s_barrier();
    __builtin_amdgcn_sched_barrier(0);

    i32x4 af[4], bg[4];
    const char* base = smem + buf * 16384;
#pragma unroll
    for (int i = 0; i < 4; ++i) {
      af[i] = *(const i32x4*)(base + (wm + (i << 4) + lrow) * 64 + koff);
      bg[i] = *(const i32x4*)(base + 8192 + (wn + (i << 4) + lrow) * 64 + koff);
    }

    if (t + 2 < nt) {
      int pb = buf + 2;
      if (pb >= 3) pb -= 3;
      stage(t + 2, pb);
    }

    asm volatile("s_waitcnt lgkmcnt(0)" ::: "memory");
    __builtin_amdgcn_sched_barrier(0);  // rule #18

#pragma unroll
    for (int i = 0; i < 4; ++i)
#pragma unroll
      for (int j = 0; j < 4; ++j)
        acc[i][j] =
            __builtin_amdgcn_mfma_i32_16x16x64_i8(af[i], bg[j], acc[i][j], 0, 0, 0);

    if (++buf == 3) buf = 0;
  }

  // epilogue: C/D layout col=lane&15, row=(lane>>4)*4+reg
  const int col0 = n0 + wn + lrow;
  const int rowb = m0 + wm + ((lane >> 4) << 2);
  float sb[4], bi[4];
#pragma unroll
  for (int j = 0; j < 4; ++j) {
    sb[j] = sB[col0 + (j << 4)];
    if (EPI == 0) bi[j] = bias[col0 + (j << 4)];
  }
#pragma unroll
  for (int i = 0; i < 4; ++i)
#pragma unroll
    for (int r = 0; r < 4; ++r) {
      const int row = rowb + (i << 4) + r;
      const float sa = (EPI == 1) ? sA[row] : (1.0f / 127.0f);
#pragma unroll
      for (int j = 0; j < 4; ++j) {
        const size_t idx = (size_t)row * N + (col0 + (j << 4));
        const float v = (float)acc[i][j][r] * (sa * sb[j]);
        if (EPI == 1) {
          ((bf16*)C)[idx] = (bf16)(1.0f / (1.0f + __expf(-v)));
        } else {
          ((float*)C)[idx] = v + bi[j];
        }
      }
    }
}

// ---------------------------------------------------------------------------
// Windowed Hamming attention.  One thread per (b,s,h).  Gate is folded into
// the output GEMM (W2 = Wo .* (emb1-emb0), bias = Wo @ emb0), so this emits
// raw o in [0,1] quantized to i8 with fixed scale 127.
// ---------------------------------------------------------------------------
__global__ __launch_bounds__(256) void rosa_attn(
    const bf16* __restrict__ qkv, signed char* __restrict__ Oq) {
  const int t = blockIdx.x * 256 + threadIdx.x;
  const int row = t >> 7;
  const int h = t & 127;
  const int sp = row & 4095;

  const bf16* qptr = qkv + (size_t)row * 3072 + h * 8;
  bf16x8 qv = *(const bf16x8*)qptr;
  float qb[8], qsum = 0.f;
#pragma unroll
  for (int c = 0; c < 8; ++c) {
    qb[c] = (float)qv[c];
    qsum += qb[c];
  }

  float oacc[8] = {};
  float wsum = 0.f;
  const int wmax = (sp + 1 < 8) ? (sp + 1) : 8;
  const float scale = 0.35355339059327373f;

  for (int d = 0; d < wmax; ++d) {
    const bf16* base = qkv + (size_t)(row - d) * 3072 + h * 8;
    bf16x8 kv = *(const bf16x8*)(base + 1024);
    bf16x8 vv = *(const bf16x8*)(base + 2048);
    float dot = 0.f, ksum = 0.f;
#pragma unroll
    for (int c = 0; c < 8; ++c) {
      const float kb = (float)kv[c];
      dot += qb[c] * kb;
      ksum += kb;
    }
    const float score = (8.0f + 2.0f * dot - qsum - ksum) * scale;
    const float w = __expf(score);
    wsum += w;
#pragma unroll
    for (int c = 0; c < 8; ++c) oacc[c] += w * (float)vv[c];
  }

  const float inv = 127.0f / wsum;
  scx8 outv;
#pragma unroll
  for (int c = 0; c < 8; ++c)
    outv[c] = (signed char)(int)(oacc[c] * inv + 0.5f);  // o in [0,1]
  *(scx8*)(Oq + (size_t)row * 1024 + h * 8) = outv;
}

// ---------------------------------------------------------------------------
// Per-row i8 quantization.  One block (256 thr) per 1024-elem row.
// blocks [0,8192): X rows -> Xq, sx
// blocks [8192,11264): Wq/Wk/Wv rows -> Wqkvq, sw
// blocks [11264,12288): W2 rows = Wo[r,:]*(emb1-emb0) -> W2q, sw2; also
//                       bias[r] = dot(Wo[r,:], emb0)
// ---------------------------------------------------------------------------
__global__ __launch_bounds__(256) void quant_all(
    const float* __restrict__ X, const float* __restrict__ Wq,
    const float* __restrict__ Wk, const float* __restrict__ Wv,
    const float* __restrict__ Wo, const float* __restrict__ emb0,
    const float* __restrict__ emb1, signed char* __restrict__ Xq,
    signed char* __restrict__ Wqkvq, signed char* __restrict__ W2q,
    float* __restrict__ sx, float* __restrict__ sw, float* __restrict__ sw2,
    float* __restrict__ bias) {
  __shared__ float redm[4], reds[4];
  const int b = blockIdx.x, tid = threadIdx.x;
  const float* srow;
  signed char* drow;
  float* sc;
  bool isW2 = false;
  int w2r = 0;
  if (b < 8192) {
    srow = X + (size_t)b * 1024; drow = Xq + (size_t)b * 1024; sc = sx + b;
  } else if (b < 11264) {
    const int r = b - 8192;
    const float* w = (r < 1024) ? Wq : (r < 2048 ? Wk : Wv);
    srow = w + (size_t)(r & 1023) * 1024;
    drow = Wqkvq + (size_t)r * 1024; sc = sw + r;
  } else {
    const int r = b - 11264; w2r = r;
    srow = Wo + (size_t)r * 1024; drow = W2q + (size_t)r * 1024; sc = sw2 + r;
    isW2 = true;
  }
  float4 v = ((const float4*)srow)[tid];
  float bsum = 0.f;
  if (isW2) {
    const float4 e1 = ((const float4*)emb1)[tid];
    const float4 e0 = ((const float4*)emb0)[tid];
    bsum = v.x * e0.x + v.y * e0.y + v.z * e0.z + v.w * e0.w;
    v.x *= (e1.x - e0.x); v.y *= (e1.y - e0.y);
    v.z *= (e1.z - e0.z); v.w *= (e1.w - e0.w);
  }
  float m = fmaxf(fmaxf(fabsf(v.x), fabsf(v.y)), fmaxf(fabsf(v.z), fabsf(v.w)));
#pragma unroll
  for (int off = 32; off; off >>= 1) m = fmaxf(m, __shfl_xor(m, off));
#pragma unroll
  for (int off = 32; off; off >>= 1) bsum += __shfl_xor(bsum, off);
  if ((tid & 63) == 0) { redm[tid >> 6] = m; reds[tid >> 6] = bsum; }
  __syncthreads();
  const float mx = fmaxf(fmaxf(redm[0], redm[1]), fmaxf(redm[2], redm[3]));
  const float inv = (mx > 0.f) ? 127.f / mx : 0.f;
  const int q0 = __float2int_rn(v.x * inv) & 255;
  const int q1 = __float2int_rn(v.y * inv) & 255;
  const int q2 = __float2int_rn(v.z * inv) & 255;
  const int q3 = __float2int_rn(v.w * inv) & 255;
  ((int*)drow)[tid] = q0 | (q1 << 8) | (q2 << 16) | (q3 << 24);
  if (tid == 0) {
    *sc = (mx > 0.f) ? mx / 127.f : 0.f;
    if (isW2) bias[w2r] = reds[0] + reds[1] + reds[2] + reds[3];
  }
}

// ---------------------------------------------------------------------------
extern "C" void kernel_launch(void* const* d_in, const int* in_sizes, int n_in,
                              void* d_out, int out_size, void* d_ws,
                              size_t ws_size, hipStream_t stream) {
  const float* X = (const float*)d_in[0];
  const float* Wq = (const float*)d_in[1];
  const float* Wk = (const float*)d_in[2];
  const float* Wv = (const float*)d_in[3];
  const float* Wo = (const float*)d_in[4];
  const float* emb0 = (const float*)d_in[5];
  const float* emb1 = (const float*)d_in[6];

  char* ws = (char*)d_ws;
  signed char* Xq    = (signed char*)(ws + 0);         // 8192*1024  (8 MB)
  signed char* Wqkvq = (signed char*)(ws + 8388608);   // 3072*1024  (3 MB)
  signed char* W2q   = (signed char*)(ws + 11534336);  // 1024*1024  (1 MB)
  float* sx   = (float*)(ws + 12582912);               // 8192 f32
  float* sw   = (float*)(ws + 12615680);               // 3072 f32
  float* sw2  = (float*)(ws + 12627968);               // 1024 f32
  float* bias = (float*)(ws + 12632064);               // 1024 f32
  bf16* QKVb  = (bf16*)(ws + 16777216);                // 8192*3072 bf16 (48 MB)
  signed char* Oq = (signed char*)(ws + 67108864);     // 8192*1024  (8 MB)
  float* out = (float*)d_out;

  // per-row i8 quantization of X, Wq|Wk|Wv, W2 (gate folded) + bias GEMV
  quant_all<<<12288, 256, 0, stream>>>(X, Wq, Wk, Wv, Wo, emb0, emb1, Xq,
                                       Wqkvq, W2q, sx, sw, sw2, bias);

  // fused QKV projection (i8 MFMA) + sigmoid -> bf16 (M=8192,N=3072,K=1024)
  gemm_i8<1><<<1536, 256, 0, stream>>>(Xq, Wqkvq, sx, sw, nullptr, QKVb, 8192,
                                       3072, 1024);

  // windowed attention -> raw o as i8 (scale 127)
  rosa_attn<<<4096, 256, 0, stream>>>(QKVb, Oq);

  // output projection (i8 MFMA) + bias -> f32 (M=8192,N=1024,K=1024)
  gemm_i8<0><<<512, 256, 0, stream>>>(Oq, W2q, nullptr, sw2, bias, out, 8192,
                                      1024, 1024);
}